// Round 3
// baseline (219.358 us; speedup 1.0000x reference)
//
#include <hip/hip_runtime.h>

// SiamNet_D: tracking IOU loss.
// Algebra: 2-way softmax score is monotone in d = l1 - l0, so argmax(score)
// == argmax(d). The loss reads only the argmax anchor per batch, so locs
// (102 MB) contributes 4 gathered floats/batch and anchors one row; only
// clss (51.2 MB) is fully scanned -> pure memory-bound scan (~7.5 us floor).
//
// R3: single fused kernel (last-block-done finalize; deterministic reduce),
// direct coalesced scalar loads (R2 showed LDS staging is neutral: lane i ->
// consecutive 4B is already one transaction/wave), full occupancy.

#define NANCH 3125   // 5*25*25
#define NB    2048

__global__ __launch_bounds__(256) void siam_fused(
    const float* __restrict__ bboxs,
    const float* __restrict__ bboxs_prev,
    const float* __restrict__ clss,
    const float* __restrict__ locs,
    const float* __restrict__ anchors,
    const float* __restrict__ LR,
    float* __restrict__ ws_iou,          // [NB] per-batch IOU
    unsigned int* __restrict__ ticket,   // zeroed via hipMemsetAsync
    float* __restrict__ out)
{
    const int b   = blockIdx.x;
    const int tid = threadIdx.x;

    // l0(a) = clss[b*6250 + a], l1(a) = clss[b*6250 + 3125 + a]
    const float* c0 = clss + (size_t)b * (2 * NANCH);
    const float* c1 = c0 + NANCH;

    // Per-thread argmax of d = l1 - l0 (ascending a, strict '>' keeps the
    // first-index tie-break; sigmoid is strictly monotone so ties map 1:1).
    float bestd = -3.402823466e+38f;
    int   besta = 0;
    for (int a = tid; a < NANCH; a += 256) {
        float d = c1[a] - c0[a];
        if (d > bestd) { bestd = d; besta = a; }
    }

    // Wave(64) reduce, tie-break toward smaller anchor index.
    #pragma unroll
    for (int off = 32; off > 0; off >>= 1) {
        float od = __shfl_down(bestd, off, 64);
        int   oa = __shfl_down(besta, off, 64);
        if (od > bestd || (od == bestd && oa < besta)) { bestd = od; besta = oa; }
    }

    __shared__ float sd[4];
    __shared__ int   sa[4];
    __shared__ bool  sLast;
    if ((tid & 63) == 0) { sd[tid >> 6] = bestd; sa[tid >> 6] = besta; }
    __syncthreads();

    if (tid == 0) {
        bestd = sd[0]; besta = sa[0];
        #pragma unroll
        for (int w = 1; w < 4; ++w) {
            if (sd[w] > bestd || (sd[w] == bestd && sa[w] < besta)) {
                bestd = sd[w]; besta = sa[w];
            }
        }
        const int a = besta;

        // score at argmax, computed like jax.nn.softmax (subtract max, exp)
        float v0 = c0[a];
        float v1 = c1[a];
        float m  = fmaxf(v0, v1);
        float e0 = expf(v0 - m);
        float e1 = expf(v1 - m);
        float s  = e1 / (e0 + e1);
        float lr = LR[0] * s;

        // locs2[i][a][b] = locs_flat[b*12500 + i*3125 + a]
        const float* lb = locs + (size_t)b * (4 * NANCH);
        float t0 = lb[0 * NANCH + a];
        float t1 = lb[1 * NANCH + a];
        float t2 = lb[2 * NANCH + a];
        float t3 = lb[3 * NANCH + a];

        float ax = anchors[a * 4 + 0];
        float ay = anchors[a * 4 + 1];
        float aw = anchors[a * 4 + 2];
        float ah = anchors[a * 4 + 3];

        float dx = t0 * aw + ax;
        float dy = t1 * ah + ay;
        float dw = expf(t2) * aw;
        float dh = expf(t3) * ah;

        float bp0 = bboxs_prev[b * 4 + 0];
        float bp1 = bboxs_prev[b * 4 + 1];
        float bp2 = bboxs_prev[b * 4 + 2];
        float bp3 = bboxs_prev[b * 4 + 3];

        float width  = bp2 * (1.0f - lr) + dw * lr;
        float height = bp3 * (1.0f - lr) + dh * lr;
        float cx = bp0 + (bp2 - 1.0f) * 0.5f + dx;
        float cy = bp1 + (bp3 - 1.0f) * 0.5f + dy;

        float A0 = cx - width  * 0.5f;
        float A1 = cy - height * 0.5f;
        float A2 = width;
        float A3 = height;
        float B0 = bboxs[b * 4 + 0];
        float B1 = bboxs[b * 4 + 1];
        float B2 = bboxs[b * 4 + 2];
        float B3 = bboxs[b * 4 + 3];

        // _iou treats [.,2]/[.,3] as x2/y2 in intersection AND area terms
        // (even though box_a holds w/h) -- replicate exactly.
        float xi = fmaxf(A0, B0);
        float yi = fmaxf(A1, B1);
        float wi = fmaxf(fminf(A2, B2) - xi, 0.0f);
        float hi = fmaxf(fminf(A3, B3) - yi, 0.0f);
        float area_i = wi * hi;
        float area_a = (A2 - A0) * (A3 - A1);
        float area_b = (B2 - B0) * (B3 - B1);
        float iou = area_i / fmaxf(area_a + area_b - area_i, 1e-5f);

        ws_iou[b] = iou;

        // release: make ws_iou[b] visible device-wide, then take a ticket.
        __threadfence();
        unsigned int old = atomicAdd(ticket, 1u);
        sLast = (old == NB - 1);
    }
    __syncthreads();

    // Last block to finish performs the (deterministic) final reduction.
    if (sLast) {
        __threadfence();   // acquire: invalidate stale L1/L2 before reads
        float s = 0.0f;
        for (int i = tid; i < NB; i += 256) s += ws_iou[i];
        #pragma unroll
        for (int off = 32; off > 0; off >>= 1) s += __shfl_down(s, off, 64);
        if ((tid & 63) == 0) sd[tid >> 6] = s;
        __syncthreads();
        if (tid == 0)
            out[0] = 1.0f - (sd[0] + sd[1] + sd[2] + sd[3]) * (1.0f / 2048.0f);
    }
}

extern "C" void kernel_launch(void* const* d_in, const int* in_sizes, int n_in,
                              void* d_out, int out_size, void* d_ws, size_t ws_size,
                              hipStream_t stream) {
    const float* bboxs      = (const float*)d_in[0];
    const float* bboxs_prev = (const float*)d_in[1];
    const float* clss       = (const float*)d_in[2];
    const float* locs       = (const float*)d_in[3];
    const float* anchors    = (const float*)d_in[4];
    const float* LR         = (const float*)d_in[5];
    float*       out        = (float*)d_out;

    float*        ws_iou = (float*)d_ws;                       // 2048 floats
    unsigned int* ticket = (unsigned int*)((char*)d_ws + 16384); // past ws_iou

    // Zero the ticket (d_ws is poisoned 0xAA before every timed launch).
    hipMemsetAsync(ticket, 0, sizeof(unsigned int), stream);

    siam_fused<<<NB, 256, 0, stream>>>(bboxs, bboxs_prev, clss, locs,
                                       anchors, LR, ws_iou, ticket, out);
}

// Round 4
// 172.100 us; speedup vs baseline: 1.2746x; 1.2746x over previous
//
#include <hip/hip_runtime.h>

// SiamNet_D: tracking IOU loss.
// Algebra: 2-way softmax score is monotone in d = l1 - l0, so argmax(score)
// == argmax(d). The loss reads only the argmax anchor per batch, so locs
// (102 MB) contributes 4 gathered floats/batch; only clss (51.2 MB) is fully
// scanned.
//
// R4: R3 showed the scan is LATENCY-bound (70.9us, 382 GB/s, VGPR=12 -> no
// unroll, ~2 outstanding loads/wave) and the atomic-ticket fusion regressed
// (2048 same-address device-scope atomics serialize at the cross-XCD
// coherence point). Fix: revert to 2 kernels; preload all 13 samples/thread
// of c0 and c1 into registers (26 independent loads in flight/wave) before
// the compare chain.

#define NANCH 3125   // 5*25*25
#define NB    2048
#define NITER 13     // ceil(3125/256); k=12 is partial (tid < 53)

__global__ __launch_bounds__(256) void siam_argmax_iou(
    const float* __restrict__ bboxs,
    const float* __restrict__ bboxs_prev,
    const float* __restrict__ clss,
    const float* __restrict__ locs,
    const float* __restrict__ anchors,
    const float* __restrict__ LR,
    float* __restrict__ ws_iou)
{
    const int b   = blockIdx.x;
    const int tid = threadIdx.x;

    // l0(a) = clss[b*6250 + a], l1(a) = clss[b*6250 + 3125 + a]
    const float* c0 = clss + (size_t)b * (2 * NANCH);
    const float* c1 = c0 + NANCH;

    // ---- Preload into registers: 26 independent loads in flight ----
    float v0[NITER], v1[NITER];
    #pragma unroll
    for (int k = 0; k < NITER; ++k) {
        int a  = tid + (k << 8);
        int ac = (a < NANCH) ? a : (NANCH - 1);   // clamp: stays in-bounds
        v0[k] = c0[ac];
        v1[k] = c1[ac];
    }

    // ---- Register argmax (ascending a, strict '>' = first-index tie-break) ----
    float bestd = -3.402823466e+38f;
    int   besta = 0;
    #pragma unroll
    for (int k = 0; k < NITER; ++k) {
        int   a = tid + (k << 8);
        float d = v1[k] - v0[k];
        if (a < NANCH && d > bestd) { bestd = d; besta = a; }
    }

    // Wave(64) reduce, tie-break toward smaller anchor index.
    #pragma unroll
    for (int off = 32; off > 0; off >>= 1) {
        float od = __shfl_down(bestd, off, 64);
        int   oa = __shfl_down(besta, off, 64);
        if (od > bestd || (od == bestd && oa < besta)) { bestd = od; besta = oa; }
    }

    __shared__ float sd[4];
    __shared__ int   sa[4];
    if ((tid & 63) == 0) { sd[tid >> 6] = bestd; sa[tid >> 6] = besta; }
    __syncthreads();

    if (tid == 0) {
        bestd = sd[0]; besta = sa[0];
        #pragma unroll
        for (int w = 1; w < 4; ++w) {
            if (sd[w] > bestd || (sd[w] == bestd && sa[w] < besta)) {
                bestd = sd[w]; besta = sa[w];
            }
        }
        const int a = besta;

        // score at argmax, computed like jax.nn.softmax (subtract max, exp)
        float x0 = c0[a];
        float x1 = c1[a];
        float m  = fmaxf(x0, x1);
        float e0 = expf(x0 - m);
        float e1 = expf(x1 - m);
        float s  = e1 / (e0 + e1);
        float lr = LR[0] * s;

        // locs2[i][a][b] = locs_flat[b*12500 + i*3125 + a]
        const float* lb = locs + (size_t)b * (4 * NANCH);
        float t0 = lb[0 * NANCH + a];
        float t1 = lb[1 * NANCH + a];
        float t2 = lb[2 * NANCH + a];
        float t3 = lb[3 * NANCH + a];

        float ax = anchors[a * 4 + 0];
        float ay = anchors[a * 4 + 1];
        float aw = anchors[a * 4 + 2];
        float ah = anchors[a * 4 + 3];

        float dx = t0 * aw + ax;
        float dy = t1 * ah + ay;
        float dw = expf(t2) * aw;
        float dh = expf(t3) * ah;

        float bp0 = bboxs_prev[b * 4 + 0];
        float bp1 = bboxs_prev[b * 4 + 1];
        float bp2 = bboxs_prev[b * 4 + 2];
        float bp3 = bboxs_prev[b * 4 + 3];

        float width  = bp2 * (1.0f - lr) + dw * lr;
        float height = bp3 * (1.0f - lr) + dh * lr;
        float cx = bp0 + (bp2 - 1.0f) * 0.5f + dx;
        float cy = bp1 + (bp3 - 1.0f) * 0.5f + dy;

        float A0 = cx - width  * 0.5f;
        float A1 = cy - height * 0.5f;
        float A2 = width;
        float A3 = height;
        float B0 = bboxs[b * 4 + 0];
        float B1 = bboxs[b * 4 + 1];
        float B2 = bboxs[b * 4 + 2];
        float B3 = bboxs[b * 4 + 3];

        // _iou treats [.,2]/[.,3] as x2/y2 in intersection AND area terms
        // (even though box_a holds w/h) -- replicate exactly.
        float xi = fmaxf(A0, B0);
        float yi = fmaxf(A1, B1);
        float wi = fmaxf(fminf(A2, B2) - xi, 0.0f);
        float hi = fmaxf(fminf(A3, B3) - yi, 0.0f);
        float area_i = wi * hi;
        float area_a = (A2 - A0) * (A3 - A1);
        float area_b = (B2 - B0) * (B3 - B1);
        float iou = area_i / fmaxf(area_a + area_b - area_i, 1e-5f);

        ws_iou[b] = iou;
    }
}

__global__ __launch_bounds__(256) void siam_finalize(
    const float* __restrict__ ws_iou, float* __restrict__ out)
{
    const int tid = threadIdx.x;
    float s = 0.0f;
    for (int i = tid; i < NB; i += 256) s += ws_iou[i];
    #pragma unroll
    for (int off = 32; off > 0; off >>= 1) s += __shfl_down(s, off, 64);

    __shared__ float sd[4];
    if ((tid & 63) == 0) sd[tid >> 6] = s;
    __syncthreads();
    if (tid == 0) {
        float t = sd[0] + sd[1] + sd[2] + sd[3];
        out[0] = 1.0f - t * (1.0f / 2048.0f);
    }
}

extern "C" void kernel_launch(void* const* d_in, const int* in_sizes, int n_in,
                              void* d_out, int out_size, void* d_ws, size_t ws_size,
                              hipStream_t stream) {
    const float* bboxs      = (const float*)d_in[0];
    const float* bboxs_prev = (const float*)d_in[1];
    const float* clss       = (const float*)d_in[2];
    const float* locs       = (const float*)d_in[3];
    const float* anchors    = (const float*)d_in[4];
    const float* LR         = (const float*)d_in[5];
    float*       out        = (float*)d_out;
    float*       ws         = (float*)d_ws;   // 2048 floats of per-batch IOU

    siam_argmax_iou<<<NB, 256, 0, stream>>>(bboxs, bboxs_prev, clss, locs,
                                            anchors, LR, ws);
    siam_finalize<<<1, 256, 0, stream>>>(ws, out);
}